// Round 7
// baseline (319.984 us; speedup 1.0000x reference)
//
#include <hip/hip_runtime.h>

// ---------------------------------------------------------------------------
// PointTransformerForSegmentation, round 12:
//   convert   : bf16-cast w0feat / w0pos / w1 / feat2
//   fgemm     : F[b*128+n2][512] = feat2 . W0feat^T   (f32, tiny GEMM)
//   build_h0  : kNN + pos embed + K=32 MFMA + F gather -> H0 plane-major bf16
//   gemm2     : BARRIER-FREE wave-private GEMM. Each wave owns a 64q x 64n
//               output tile and a private 16KB LDS slice (2-deep dbuf of its
//               own A 4KB + B 4KB per BK=32 step). Zero s_barrier: wave
//               self-paces with counted s_waitcnt vmcnt(8); the only hazard
//               (DMA overwrite of the buffer being read) is fenced by a
//               wave-local lgkmcnt(0). 48 K-steps = 3 j-planes x 16,
//               register relu-fold at plane boundaries. Swapped-operand MFMA
//               -> epilogue writes 64B-contiguous n1 runs. 8 waves of a
//               block share the q-tile (A stages L1-hot); XCD-partitioned
//               q-panels keep A L2-resident per XCD.
// LDS layout: fragment-linear 1KB groups (16 rows x 32 k), lane l at
// group*1024 + l*16 -> sequential banks, zero conflicts.
// ---------------------------------------------------------------------------

typedef unsigned short u16;
typedef __bf16 bf16x8 __attribute__((ext_vector_type(8)));
typedef float f32x4 __attribute__((ext_vector_type(4)));
typedef u16 u16x4 __attribute__((ext_vector_type(4)));
typedef u16 u16x8 __attribute__((ext_vector_type(8)));

#define BQ 8
#define N1Q 2048
#define N2Q 128
#define C2Q 256
#define DPOS 32
#define H0Q 512
#define H1Q 1024
#define NQ (BQ * N1Q)   // 16384 queries

// workspace layout (bytes)
#define WS_W0F 0u          // 512*256*2   = 262144
#define WS_W0P 262144u     // 512*32*2    = 32768
#define WS_W1 294912u      // 1024*512*2  = 1048576
#define WS_F2B 1343488u    // 1024*256*2  = 524288
#define WS_F 1867776u      // 1024*512*4  = 2097152
#define WS_H0 3964928u     // 3*16384*512*2 = 50331648 (end 54296576)

__device__ __forceinline__ u16 f2bf(float f) {
  unsigned int u = __builtin_bit_cast(unsigned int, f);
  return (u16)((u + 0x7FFFu + ((u >> 16) & 1u)) >> 16);
}

__device__ __forceinline__ void load16_lds(const void* g, void* l) {
  __builtin_amdgcn_global_load_lds(
      (const __attribute__((address_space(1))) unsigned int*)g,
      (__attribute__((address_space(3))) unsigned int*)l, 16, 0, 0);
}

// ---------------------------------------------------------------------------
// convert: w0feat (512x256), w0pos (512x32), w1 (1024x512), feat2 (1024x256)
__global__ void convert_inputs(const float* __restrict__ w0,
                               const float* __restrict__ w1,
                               const float* __restrict__ feat2,
                               u16* __restrict__ w0f, u16* __restrict__ w0p,
                               u16* __restrict__ w1b, u16* __restrict__ f2b) {
  int i = blockIdx.x * 256 + threadIdx.x;  // grid covers 933888 exactly
  if (i < 131072) {
    int h = i >> 8, c = i & 255;
    w0f[i] = f2bf(w0[h * 288 + c]);
  } else if (i < 147456) {
    int j = i - 131072;
    int h = j >> 5, c = j & 31;
    w0p[j] = f2bf(w0[h * 288 + 256 + c]);
  } else if (i < 671744) {
    int j = i - 147456;
    w1b[j] = f2bf(w1[j]);
  } else {
    int j = i - 671744;  // < 262144
    f2b[j] = f2bf(feat2[j]);
  }
}

// ---------------------------------------------------------------------------
// fgemm: F[m][n] = sum_k feat2bf[m][k]*w0featbf[n][k], f32 out.
// M=1024 N=512 K=256, 128x128 tile, 32 blocks.
__global__ __launch_bounds__(256, 2) void fgemm(const u16* __restrict__ A,
                                                const u16* __restrict__ W,
                                                float* __restrict__ F) {
  __shared__ alignas(16) u16 As[128 * 32];
  __shared__ alignas(16) u16 Bs[128 * 32];
  const int m0 = (blockIdx.x >> 2) * 128, n0 = (blockIdx.x & 3) * 128;
  const int t = threadIdx.x;
  const int wv = t >> 6, lane = t & 63;
  const int wm = wv >> 1, wn = wv & 1;
  const int quad = lane >> 4, cc = lane & 15;
  const int srow = lane & 15, skc = quad * 8;
  f32x4 acc[4][4] = {};

  for (int k0 = 0; k0 < 256; k0 += 32) {
#pragma unroll
    for (int i = 0; i < 2; i++) {
      int g = i * 4 + wv;
      load16_lds(A + (size_t)(m0 + g * 16 + srow) * 256 + k0 + skc,
                 (char*)As + g * 1024 + (lane << 4));
      load16_lds(W + (size_t)(n0 + g * 16 + srow) * 256 + k0 + skc,
                 (char*)Bs + g * 1024 + (lane << 4));
    }
    __syncthreads();
    bf16x8 af[4], bf[4];
#pragma unroll
    for (int mt = 0; mt < 4; mt++)
      af[mt] = *(const bf16x8*)((const char*)As + (wm * 4 + mt) * 1024 + (lane << 4));
#pragma unroll
    for (int nt = 0; nt < 4; nt++)
      bf[nt] = *(const bf16x8*)((const char*)Bs + (wn * 4 + nt) * 1024 + (lane << 4));
#pragma unroll
    for (int mt = 0; mt < 4; mt++)
#pragma unroll
      for (int nt = 0; nt < 4; nt++)
        acc[mt][nt] = __builtin_amdgcn_mfma_f32_16x16x32_bf16(
            af[mt], bf[nt], acc[mt][nt], 0, 0, 0);
    __syncthreads();
  }

#pragma unroll
  for (int nt = 0; nt < 4; nt++) {
    int gn = n0 + wn * 64 + nt * 16 + cc;
#pragma unroll
    for (int mt = 0; mt < 4; mt++) {
      int gm = m0 + wm * 64 + mt * 16 + quad * 4;
#pragma unroll
      for (int r = 0; r < 4; r++)
        F[(size_t)(gm + r) * H0Q + gn] = acc[mt][nt][r];
    }
  }
}

// ---------------------------------------------------------------------------
// build_h0: block = 64 queries (256 blocks).
// Phase 1a: 4-way-parallel kNN scan. Phase 1b: t<64 merge (serial tie order).
// Phase 1c: t<192 pos embed. Phase 2: per 128-col slice, MFMA + F-gather +
// scale/bias/relu into LDS hstage, then COALESCED 16B-chunk H0 row writes.
__global__ __launch_bounds__(256, 2) void build_h0(
    const float* __restrict__ xyz1, const float* __restrict__ xyz2,
    const float* __restrict__ lrf2, const float* __restrict__ w_pos,
    const float* __restrict__ pscale, const float* __restrict__ pbias,
    const u16* __restrict__ w0p, const float* __restrict__ F,
    const float* __restrict__ s0, const float* __restrict__ b0,
    u16* __restrict__ H0) {
  __shared__ float xyz2s[N2Q * 3];
  __shared__ float n2s[N2Q];
  __shared__ float lrfs[N2Q * 9];
  __shared__ float wps[DPOS * 4];
  __shared__ float pss[DPOS];
  __shared__ float pbs[DPOS];
  __shared__ int idxb[192];
  __shared__ float candd[64 * 13];  // stride 13: conflict-free merge reads
  __shared__ int candi[64 * 13];
  __shared__ alignas(16) u16 posb[12 * 512];     // 12 groups x (16 rows x 32)
  __shared__ alignas(16) u16 hstage[192 * 136];  // slice out, stride 136 u16

  const int t = threadIdx.x;
  const int qb = blockIdx.x * 64;
  const int b = qb >> 11;

  for (int i = t; i < N2Q * 3; i += 256) xyz2s[i] = xyz2[b * N2Q * 3 + i];
  for (int i = t; i < N2Q * 9; i += 256) lrfs[i] = lrf2[b * N2Q * 9 + i];
  if (t < DPOS * 4) wps[t] = w_pos[t];
  if (t < DPOS) { pss[t] = pscale[t]; pbs[t] = pbias[t]; }
  __syncthreads();
  if (t < N2Q) {
    float x = xyz2s[t * 3], y = xyz2s[t * 3 + 1], z = xyz2s[t * 3 + 2];
    n2s[t] = x * x + y * y + z * z;
  }
  __syncthreads();

  // ---- phase 1a: partial kNN, 4 threads per query ----
  {
    const int ql = t >> 2, qt = t & 3;
    const int q = qb + ql;
    const float px = xyz1[q * 3], py = xyz1[q * 3 + 1], pz = xyz1[q * 3 + 2];
    const float pn = px * px + py * py + pz * pz;
    float d0 = 1e30f, d1 = 1e30f, d2v = 1e30f;
    int i0 = 0, i1 = 0, i2 = 0;
    const int ibeg = qt * 32;
    for (int i = ibeg; i < ibeg + 32; i++) {
      float dt = px * xyz2s[i * 3] + py * xyz2s[i * 3 + 1] + pz * xyz2s[i * 3 + 2];
      float d = pn + n2s[i] - 2.f * dt;
      if (d < d0) {
        d2v = d1; i2 = i1; d1 = d0; i1 = i0; d0 = d; i0 = i;
      } else if (d < d1) {
        d2v = d1; i2 = i1; d1 = d; i1 = i;
      } else if (d < d2v) {
        d2v = d; i2 = i;
      }
    }
    int base = ql * 13 + qt * 3;
    candd[base] = d0;      candi[base] = i0;
    candd[base + 1] = d1;  candi[base + 1] = i1;
    candd[base + 2] = d2v; candi[base + 2] = i2;
  }
  __syncthreads();

  // ---- phase 1b: merge 12 candidates per query (t<64) ----
  if (t < 64) {
    float d0 = 1e30f, d1 = 1e30f, d2v = 1e30f;
    int i0 = 0, i1 = 0, i2 = 0;
    int base = t * 13;
#pragma unroll
    for (int c = 0; c < 12; c++) {
      float d = candd[base + c];
      int id = candi[base + c];
      if (d < d0) {
        d2v = d1; i2 = i1; d1 = d0; i1 = i0; d0 = d; i0 = id;
      } else if (d < d1) {
        d2v = d1; i2 = i1; d1 = d; i1 = id;
      } else if (d < d2v) {
        d2v = d; i2 = id;
      }
    }
    idxb[t] = i0;
    idxb[64 + t] = i1;
    idxb[128 + t] = i2;
  }
  __syncthreads();

  // ---- phase 1c: pos embed, one (query, neighbor) per thread (t<192) ----
  if (t < 192) {
    const int ql = t & 63;
    const int q = qb + ql;
    const float px = xyz1[q * 3], py = xyz1[q * 3 + 1], pz = xyz1[q * 3 + 2];
    const int id = idxb[t];
    float rx = px - xyz2s[id * 3];
    float ry = py - xyz2s[id * 3 + 1];
    float rz = pz - xyz2s[id * 3 + 2];
    float rn = sqrtf(rx * rx + ry * ry + rz * rz);
    float inv = 1.f / fmaxf(rn, 1e-12f);
    float ux = rx * inv, uy = ry * inv, uz = rz * inv;
    const float* L = lrfs + id * 9;
    float a0 = L[0] * ux + L[1] * uy + L[2] * uz;
    float a1 = L[3] * ux + L[4] * uy + L[5] * uz;
    float a2 = L[6] * ux + L[7] * uy + L[8] * uz;
    u16* pd = posb + (t >> 4) * 512 + (t & 15) * 8;
#pragma unroll
    for (int o = 0; o < DPOS; o++) {
      float v = wps[o * 4] * rn + wps[o * 4 + 1] * a0 + wps[o * 4 + 2] * a1 +
                wps[o * 4 + 3] * a2;
      v = v * pss[o] + pbs[o];
      v = (v >= 0.f) ? v : 0.2f * v;  // LeakyReLU(0.2)
      pd[(o >> 3) * 128 + (o & 7)] = f2bf(v);
    }
  }
  __syncthreads();

  // ---- phase 2: H0 = relu((F[idx] + pos.W0pos^T)*s0 + b0), via hstage ----
  const int wv = t >> 6, lane = t & 63;
  const int quad = lane >> 4, cc = lane & 15;
  const float* Fr[3];
  int rlv[3];
#pragma unroll
  for (int mt = 0; mt < 3; mt++) {
    int rl = wv * 48 + mt * 16 + cc;  // wave's rows: groups 3*wv+mt
    rlv[mt] = rl;
    Fr[mt] = F + ((size_t)(b * N2Q + idxb[rl])) * H0Q;
  }
  bf16x8 afr[3];
#pragma unroll
  for (int mt = 0; mt < 3; mt++)
    afr[mt] = *(const bf16x8*)((const char*)posb + (wv * 3 + mt) * 1024 + (lane << 4));
  const f32x4 zf = {};
  for (int n0s = 0; n0s < H0Q; n0s += 128) {
    bf16x8 bfr[8];
#pragma unroll
    for (int nt = 0; nt < 8; nt++)
      bfr[nt] = *(const bf16x8*)(w0p + (n0s + nt * 16 + cc) * 32 + quad * 8);
    f32x4 acc[3][8];
#pragma unroll
    for (int mt = 0; mt < 3; mt++)
#pragma unroll
      for (int nt = 0; nt < 8; nt++)  // swapped operands: C row=h, col=query
        acc[mt][nt] = __builtin_amdgcn_mfma_f32_16x16x32_bf16(bfr[nt], afr[mt],
                                                              zf, 0, 0, 0);
#pragma unroll
    for (int nt = 0; nt < 8; nt++) {
      int hb = n0s + nt * 16 + quad * 4;
      f32x4 sv = *(const f32x4*)(s0 + hb);
      f32x4 bvv = *(const f32x4*)(b0 + hb);
#pragma unroll
      for (int mt = 0; mt < 3; mt++) {
        f32x4 fv = *(const f32x4*)(Fr[mt] + hb);
        u16x4 o4;
#pragma unroll
        for (int r = 0; r < 4; r++) {
          float h = (fv[r] + acc[mt][nt][r]) * sv[r] + bvv[r];
          h = h > 0.f ? h : 0.f;
          o4[r] = f2bf(h);
        }
        // LDS stage at [row rl][col nt*16+quad*4] (u16, stride 136)
        *(u16x4*)(hstage + rlv[mt] * 136 + nt * 16 + quad * 4) = o4;
      }
    }
    __syncthreads();
    // coalesced write: 192 rows x 16 chunks of 16B; 12 chunks per thread
#pragma unroll
    for (int it = 0; it < 12; it++) {
      int idx = it * 256 + t;
      int rl = idx >> 4, ch = idx & 15;
      u16x8 v = *(const u16x8*)(hstage + rl * 136 + ch * 8);
      int jj = rl >> 6, ql = rl & 63;
      *(u16x8*)(H0 + ((size_t)(jj * NQ) + qb + ql) * H0Q + n0s + ch * 8) = v;
    }
    __syncthreads();
  }
}

// ---------------------------------------------------------------------------
// gemm2: out[b][n][n1] = sum_j relu((H0_j[q][:] . W1[n][:])*s1[n] + b1[n]).
// BARRIER-FREE: each wave owns a 64q x 64n output tile, a private 16KB LDS
// slice (2-deep dbuf of A 4KB + B 4KB), and runs 48 BK=32 K-steps (3 planes
// x 16) fully self-paced:
//   vmcnt(8)  [step st landed; step st+1 stays in flight]
//   8x ds_read frags  ->  lgkmcnt(0)  [wave-local: buffer fully read]
//   stage(st+2 -> same buffer)        [8 global_load_lds]
//   16x MFMA (swapped operands)       [setprio(1)]
// No s_barrier anywhere; no inter-wave hazards (private LDS regions).
// The 8 waves of a block share q0 (A stages hit L1); XCD x owns q-panels
// [x*32, x*32+32) so A stays L2-resident per XCD. Fold at st=15/31/47.
__global__ __launch_bounds__(512, 2) void gemm2(const u16* __restrict__ A,
                                                const u16* __restrict__ W,
                                                const float* __restrict__ s,
                                                const float* __restrict__ bz,
                                                float* __restrict__ out) {
  __shared__ alignas(16) char lds[8][16384];  // per-wave private 16KB
  const int id = blockIdx.x;            // 512 blocks
  const int xcd = id & 7, g = id >> 3;  // g 0..63
  const int t = threadIdx.x;
  const int wv = t >> 6, lane = t & 63;
  const int quad = lane >> 4, cc = lane & 15;
  const int lr = lane & 15, lk = quad * 8;
  const int tl = g * 8 + wv;                    // 0..511 within this XCD
  const int q0 = (xcd * 32 + (tl >> 4)) * 64;   // block's 8 waves share q0
  const int n0 = (tl & 15) * 64;

  char* const myl = (char*)lds + wv * 16384;

  // staging source bases (elements; + plane/k0 per step)
  const size_t aRow = (size_t)(q0 + lr) * 512 + lk;
  const size_t bRow = (size_t)(n0 + lr) * 512 + lk;

  // per-lane scale/bias: gn = n0 + nt*16 + quad*4 + r
  f32x4 sv4[4], bv4[4];
#pragma unroll
  for (int nt = 0; nt < 4; nt++) {
    int gnb = n0 + nt * 16 + quad * 4;
    sv4[nt] = *(const f32x4*)(s + gnb);
    bv4[nt] = *(const f32x4*)(bz + gnb);
  }
  // pin s/b in regs now so their loads retire before the counted-vmcnt loop
#pragma unroll
  for (int nt = 0; nt < 4; nt++)
#pragma unroll
    for (int r = 0; r < 4; r++) {
      float a = sv4[nt][r], c = bv4[nt][r];
      asm volatile("" : "+v"(a), "+v"(c));
      sv4[nt][r] = a; bv4[nt][r] = c;
    }

  auto stage = [&](int st, int buf) {
    const u16* Ap = A + (size_t)(st >> 4) * ((size_t)NQ * H0Q) + ((st & 15) << 5);
    const u16* Wp = W + ((st & 15) << 5);
    char* dst = myl + buf * 8192 + (lane << 4);
#pragma unroll
    for (int g2 = 0; g2 < 4; g2++)
      load16_lds(Ap + aRow + (size_t)g2 * 16 * 512, dst + g2 * 1024);
#pragma unroll
    for (int g2 = 0; g2 < 4; g2++)
      load16_lds(Wp + bRow + (size_t)g2 * 16 * 512, dst + 4096 + g2 * 1024);
  };

  f32x4 sum[4][4] = {};
  f32x4 acc[4][4] = {};

  auto step = [&](int st, bool doStage) {
    const char* bufp = myl + (st & 1) * 8192 + (lane << 4);
    bf16x8 af[4], bf[4];
#pragma unroll
    for (int mt = 0; mt < 4; mt++)
      af[mt] = *(const bf16x8*)(bufp + mt * 1024);
#pragma unroll
    for (int nt = 0; nt < 4; nt++)
      bf[nt] = *(const bf16x8*)(bufp + 4096 + nt * 1024);
    if (doStage) {
      // wave-local drain: our 8 ds_reads done -> safe to DMA-overwrite buf
      asm volatile("s_waitcnt lgkmcnt(0)" ::: "memory");
      __builtin_amdgcn_sched_barrier(0);
      stage(st + 2, st & 1);
    }
    __builtin_amdgcn_s_setprio(1);
#pragma unroll
    for (int mt = 0; mt < 4; mt++)
#pragma unroll
      for (int nt = 0; nt < 4; nt++)  // swapped: C row=gn frag, col=query
        acc[mt][nt] = __builtin_amdgcn_mfma_f32_16x16x32_bf16(
            bf[nt], af[mt], acc[mt][nt], 0, 0, 0);
    __builtin_amdgcn_s_setprio(0);
  };

  auto fold = [&]() {
#pragma unroll
    for (int mt = 0; mt < 4; mt++)
#pragma unroll
      for (int nt = 0; nt < 4; nt++) {
#pragma unroll
        for (int r = 0; r < 4; r++) {
          float h = acc[mt][nt][r] * sv4[nt][r] + bv4[nt][r];
          sum[mt][nt][r] += (h > 0.f ? h : 0.f);
        }
        acc[mt][nt] = f32x4{};
      }
  };

  stage(0, 0);
  stage(1, 1);

#pragma unroll 2
  for (int st = 0; st < 46; st++) {
    asm volatile("s_waitcnt vmcnt(8)" ::: "memory");  // step st landed
    step(st, true);
    if ((st & 15) == 15) fold();  // st 15, 31: plane boundary
  }
  asm volatile("s_waitcnt vmcnt(8)" ::: "memory");
  step(46, false);
  asm volatile("s_waitcnt vmcnt(0)" ::: "memory");
  step(47, false);
  fold();

  // epilogue: per (mt,nt,r), 16 lanes write 64B-contiguous n1 runs
  const int bb = q0 >> 11, n1b = q0 & 2047;
#pragma unroll
  for (int nt = 0; nt < 4; nt++) {
#pragma unroll
    for (int mt = 0; mt < 4; mt++) {
#pragma unroll
      for (int r = 0; r < 4; r++) {
        int gn = n0 + nt * 16 + quad * 4 + r;
        out[((size_t)bb * H1Q + gn) * N1Q + n1b + mt * 16 + cc] =
            sum[mt][nt][r];
      }
    }
  }
}

// ---------------------------------------------------------------------------
extern "C" void kernel_launch(void* const* d_in, const int* in_sizes, int n_in,
                              void* d_out, int out_size, void* d_ws,
                              size_t ws_size, hipStream_t stream) {
  const float* xyz1 = (const float*)d_in[0];
  const float* xyz2 = (const float*)d_in[1];
  const float* feat2 = (const float*)d_in[2];
  const float* lrf2 = (const float*)d_in[3];
  const float* w_pos = (const float*)d_in[4];
  const float* pscale = (const float*)d_in[5];
  const float* pbias = (const float*)d_in[6];
  const float* w0 = (const float*)d_in[7];
  const float* s0 = (const float*)d_in[8];
  const float* b0 = (const float*)d_in[9];
  const float* w1 = (const float*)d_in[10];
  const float* s1 = (const float*)d_in[11];
  const float* b1 = (const float*)d_in[12];
  float* out = (float*)d_out;

  char* ws = (char*)d_ws;
  u16* w0f = (u16*)(ws + WS_W0F);
  u16* w0p = (u16*)(ws + WS_W0P);
  u16* w1b = (u16*)(ws + WS_W1);
  u16* f2b = (u16*)(ws + WS_F2B);
  float* F = (float*)(ws + WS_F);
  u16* H0 = (u16*)(ws + WS_H0);

  convert_inputs<<<933888 / 256, 256, 0, stream>>>(w0, w1, feat2, w0f, w0p,
                                                   w1b, f2b);
  fgemm<<<32, 256, 0, stream>>>(f2b, w0f, F);
  build_h0<<<NQ / 64, 256, 0, stream>>>(xyz1, xyz2, lrf2, w_pos, pscale,
                                        pbias, w0p, F, s0, b0, H0);
  gemm2<<<512, 512, 0, stream>>>(H0, w1b, s1, b1, out);
}

// Round 8
// 244.393 us; speedup vs baseline: 1.3093x; 1.3093x over previous
//
#include <hip/hip_runtime.h>

// ---------------------------------------------------------------------------
// PointTransformerForSegmentation, round 13:
//   convert   : bf16-cast w0feat / w0pos / w1 / feat2
//   fgemm     : F[b*128+n2][512] = feat2 . W0feat^T   (f32, tiny GEMM)
//   build_h0  : kNN + pos embed + K=32 MFMA + F gather -> H0 plane-major bf16
//               (R6 version: LDS hstage -> coalesced 16B H0 row writes)
//   gemm2     : BM=128 x BN=128, BK=64, 256 thr (4 waves, 64x64/wave,
//               32 MFMA/wave/step -- R4's best ratio) with DOUBLE-buffered
//               64KB LDS -> 2 blocks/CU co-resident (the m97/m114 overlap:
//               one block's barrier stall hides under the other's MFMA).
//               Counted vmcnt(8), R4 barrier discipline, 24 K-steps
//               (3 planes x 8), register relu-fold at kt=7/15/23.
//               Swapped-operand MFMA -> epilogue writes 64B n1 runs.
// LDS layout: fragment-linear 1KB groups (16 rows x 32 k), lane l at
// group*1024 + l*16 -> sequential banks, zero conflicts.
// ---------------------------------------------------------------------------

typedef unsigned short u16;
typedef __bf16 bf16x8 __attribute__((ext_vector_type(8)));
typedef float f32x4 __attribute__((ext_vector_type(4)));
typedef u16 u16x4 __attribute__((ext_vector_type(4)));
typedef u16 u16x8 __attribute__((ext_vector_type(8)));

#define BQ 8
#define N1Q 2048
#define N2Q 128
#define C2Q 256
#define DPOS 32
#define H0Q 512
#define H1Q 1024
#define NQ (BQ * N1Q)   // 16384 queries

// workspace layout (bytes)
#define WS_W0F 0u          // 512*256*2   = 262144
#define WS_W0P 262144u     // 512*32*2    = 32768
#define WS_W1 294912u      // 1024*512*2  = 1048576
#define WS_F2B 1343488u    // 1024*256*2  = 524288
#define WS_F 1867776u      // 1024*512*4  = 2097152
#define WS_H0 3964928u     // 3*16384*512*2 = 50331648 (end 54296576)

__device__ __forceinline__ u16 f2bf(float f) {
  unsigned int u = __builtin_bit_cast(unsigned int, f);
  return (u16)((u + 0x7FFFu + ((u >> 16) & 1u)) >> 16);
}

__device__ __forceinline__ void load16_lds(const void* g, void* l) {
  __builtin_amdgcn_global_load_lds(
      (const __attribute__((address_space(1))) unsigned int*)g,
      (__attribute__((address_space(3))) unsigned int*)l, 16, 0, 0);
}

// ---------------------------------------------------------------------------
// convert: w0feat (512x256), w0pos (512x32), w1 (1024x512), feat2 (1024x256)
__global__ void convert_inputs(const float* __restrict__ w0,
                               const float* __restrict__ w1,
                               const float* __restrict__ feat2,
                               u16* __restrict__ w0f, u16* __restrict__ w0p,
                               u16* __restrict__ w1b, u16* __restrict__ f2b) {
  int i = blockIdx.x * 256 + threadIdx.x;  // grid covers 933888 exactly
  if (i < 131072) {
    int h = i >> 8, c = i & 255;
    w0f[i] = f2bf(w0[h * 288 + c]);
  } else if (i < 147456) {
    int j = i - 131072;
    int h = j >> 5, c = j & 31;
    w0p[j] = f2bf(w0[h * 288 + 256 + c]);
  } else if (i < 671744) {
    int j = i - 147456;
    w1b[j] = f2bf(w1[j]);
  } else {
    int j = i - 671744;  // < 262144
    f2b[j] = f2bf(feat2[j]);
  }
}

// ---------------------------------------------------------------------------
// fgemm: F[m][n] = sum_k feat2bf[m][k]*w0featbf[n][k], f32 out.
// M=1024 N=512 K=256, 128x128 tile, 32 blocks.
__global__ __launch_bounds__(256, 2) void fgemm(const u16* __restrict__ A,
                                                const u16* __restrict__ W,
                                                float* __restrict__ F) {
  __shared__ alignas(16) u16 As[128 * 32];
  __shared__ alignas(16) u16 Bs[128 * 32];
  const int m0 = (blockIdx.x >> 2) * 128, n0 = (blockIdx.x & 3) * 128;
  const int t = threadIdx.x;
  const int wv = t >> 6, lane = t & 63;
  const int wm = wv >> 1, wn = wv & 1;
  const int quad = lane >> 4, cc = lane & 15;
  const int srow = lane & 15, skc = quad * 8;
  f32x4 acc[4][4] = {};

  for (int k0 = 0; k0 < 256; k0 += 32) {
#pragma unroll
    for (int i = 0; i < 2; i++) {
      int g = i * 4 + wv;
      load16_lds(A + (size_t)(m0 + g * 16 + srow) * 256 + k0 + skc,
                 (char*)As + g * 1024 + (lane << 4));
      load16_lds(W + (size_t)(n0 + g * 16 + srow) * 256 + k0 + skc,
                 (char*)Bs + g * 1024 + (lane << 4));
    }
    __syncthreads();
    bf16x8 af[4], bf[4];
#pragma unroll
    for (int mt = 0; mt < 4; mt++)
      af[mt] = *(const bf16x8*)((const char*)As + (wm * 4 + mt) * 1024 + (lane << 4));
#pragma unroll
    for (int nt = 0; nt < 4; nt++)
      bf[nt] = *(const bf16x8*)((const char*)Bs + (wn * 4 + nt) * 1024 + (lane << 4));
#pragma unroll
    for (int mt = 0; mt < 4; mt++)
#pragma unroll
      for (int nt = 0; nt < 4; nt++)
        acc[mt][nt] = __builtin_amdgcn_mfma_f32_16x16x32_bf16(
            af[mt], bf[nt], acc[mt][nt], 0, 0, 0);
    __syncthreads();
  }

#pragma unroll
  for (int nt = 0; nt < 4; nt++) {
    int gn = n0 + wn * 64 + nt * 16 + cc;
#pragma unroll
    for (int mt = 0; mt < 4; mt++) {
      int gm = m0 + wm * 64 + mt * 16 + quad * 4;
#pragma unroll
      for (int r = 0; r < 4; r++)
        F[(size_t)(gm + r) * H0Q + gn] = acc[mt][nt][r];
    }
  }
}

// ---------------------------------------------------------------------------
// build_h0: block = 64 queries (256 blocks).
// Phase 1a: 4-way-parallel kNN scan. Phase 1b: t<64 merge (serial tie order).
// Phase 1c: t<192 pos embed. Phase 2: per 128-col slice, MFMA + F-gather +
// scale/bias/relu into LDS hstage, then COALESCED 16B-chunk H0 row writes.
__global__ __launch_bounds__(256, 2) void build_h0(
    const float* __restrict__ xyz1, const float* __restrict__ xyz2,
    const float* __restrict__ lrf2, const float* __restrict__ w_pos,
    const float* __restrict__ pscale, const float* __restrict__ pbias,
    const u16* __restrict__ w0p, const float* __restrict__ F,
    const float* __restrict__ s0, const float* __restrict__ b0,
    u16* __restrict__ H0) {
  __shared__ float xyz2s[N2Q * 3];
  __shared__ float n2s[N2Q];
  __shared__ float lrfs[N2Q * 9];
  __shared__ float wps[DPOS * 4];
  __shared__ float pss[DPOS];
  __shared__ float pbs[DPOS];
  __shared__ int idxb[192];
  __shared__ float candd[64 * 13];  // stride 13: conflict-free merge reads
  __shared__ int candi[64 * 13];
  __shared__ alignas(16) u16 posb[12 * 512];     // 12 groups x (16 rows x 32)
  __shared__ alignas(16) u16 hstage[192 * 136];  // slice out, stride 136 u16

  const int t = threadIdx.x;
  const int qb = blockIdx.x * 64;
  const int b = qb >> 11;

  for (int i = t; i < N2Q * 3; i += 256) xyz2s[i] = xyz2[b * N2Q * 3 + i];
  for (int i = t; i < N2Q * 9; i += 256) lrfs[i] = lrf2[b * N2Q * 9 + i];
  if (t < DPOS * 4) wps[t] = w_pos[t];
  if (t < DPOS) { pss[t] = pscale[t]; pbs[t] = pbias[t]; }
  __syncthreads();
  if (t < N2Q) {
    float x = xyz2s[t * 3], y = xyz2s[t * 3 + 1], z = xyz2s[t * 3 + 2];
    n2s[t] = x * x + y * y + z * z;
  }
  __syncthreads();

  // ---- phase 1a: partial kNN, 4 threads per query ----
  {
    const int ql = t >> 2, qt = t & 3;
    const int q = qb + ql;
    const float px = xyz1[q * 3], py = xyz1[q * 3 + 1], pz = xyz1[q * 3 + 2];
    const float pn = px * px + py * py + pz * pz;
    float d0 = 1e30f, d1 = 1e30f, d2v = 1e30f;
    int i0 = 0, i1 = 0, i2 = 0;
    const int ibeg = qt * 32;
    for (int i = ibeg; i < ibeg + 32; i++) {
      float dt = px * xyz2s[i * 3] + py * xyz2s[i * 3 + 1] + pz * xyz2s[i * 3 + 2];
      float d = pn + n2s[i] - 2.f * dt;
      if (d < d0) {
        d2v = d1; i2 = i1; d1 = d0; i1 = i0; d0 = d; i0 = i;
      } else if (d < d1) {
        d2v = d1; i2 = i1; d1 = d; i1 = i;
      } else if (d < d2v) {
        d2v = d; i2 = i;
      }
    }
    int base = ql * 13 + qt * 3;
    candd[base] = d0;      candi[base] = i0;
    candd[base + 1] = d1;  candi[base + 1] = i1;
    candd[base + 2] = d2v; candi[base + 2] = i2;
  }
  __syncthreads();

  // ---- phase 1b: merge 12 candidates per query (t<64) ----
  if (t < 64) {
    float d0 = 1e30f, d1 = 1e30f, d2v = 1e30f;
    int i0 = 0, i1 = 0, i2 = 0;
    int base = t * 13;
#pragma unroll
    for (int c = 0; c < 12; c++) {
      float d = candd[base + c];
      int id = candi[base + c];
      if (d < d0) {
        d2v = d1; i2 = i1; d1 = d0; i1 = i0; d0 = d; i0 = id;
      } else if (d < d1) {
        d2v = d1; i2 = i1; d1 = d; i1 = id;
      } else if (d < d2v) {
        d2v = d; i2 = id;
      }
    }
    idxb[t] = i0;
    idxb[64 + t] = i1;
    idxb[128 + t] = i2;
  }
  __syncthreads();

  // ---- phase 1c: pos embed, one (query, neighbor) per thread (t<192) ----
  if (t < 192) {
    const int ql = t & 63;
    const int q = qb + ql;
    const float px = xyz1[q * 3], py = xyz1[q * 3 + 1], pz = xyz1[q * 3 + 2];
    const int id = idxb[t];
    float rx = px - xyz2s[id * 3];
    float ry = py - xyz2s[id * 3 + 1];
    float rz = pz - xyz2s[id * 3 + 2];
    float rn = sqrtf(rx * rx + ry * ry + rz * rz);
    float inv = 1.f / fmaxf(rn, 1e-12f);
    float ux = rx * inv, uy = ry * inv, uz = rz * inv;
    const float* L = lrfs + id * 9;
    float a0 = L[0] * ux + L[1] * uy + L[2] * uz;
    float a1 = L[3] * ux + L[4] * uy + L[5] * uz;
    float a2 = L[6] * ux + L[7] * uy + L[8] * uz;
    u16* pd = posb + (t >> 4) * 512 + (t & 15) * 8;
#pragma unroll
    for (int o = 0; o < DPOS; o++) {
      float v = wps[o * 4] * rn + wps[o * 4 + 1] * a0 + wps[o * 4 + 2] * a1 +
                wps[o * 4 + 3] * a2;
      v = v * pss[o] + pbs[o];
      v = (v >= 0.f) ? v : 0.2f * v;  // LeakyReLU(0.2)
      pd[(o >> 3) * 128 + (o & 7)] = f2bf(v);
    }
  }
  __syncthreads();

  // ---- phase 2: H0 = relu((F[idx] + pos.W0pos^T)*s0 + b0), via hstage ----
  const int wv = t >> 6, lane = t & 63;
  const int quad = lane >> 4, cc = lane & 15;
  const float* Fr[3];
  int rlv[3];
#pragma unroll
  for (int mt = 0; mt < 3; mt++) {
    int rl = wv * 48 + mt * 16 + cc;  // wave's rows: groups 3*wv+mt
    rlv[mt] = rl;
    Fr[mt] = F + ((size_t)(b * N2Q + idxb[rl])) * H0Q;
  }
  bf16x8 afr[3];
#pragma unroll
  for (int mt = 0; mt < 3; mt++)
    afr[mt] = *(const bf16x8*)((const char*)posb + (wv * 3 + mt) * 1024 + (lane << 4));
  const f32x4 zf = {};
  for (int n0s = 0; n0s < H0Q; n0s += 128) {
    bf16x8 bfr[8];
#pragma unroll
    for (int nt = 0; nt < 8; nt++)
      bfr[nt] = *(const bf16x8*)(w0p + (n0s + nt * 16 + cc) * 32 + quad * 8);
    f32x4 acc[3][8];
#pragma unroll
    for (int mt = 0; mt < 3; mt++)
#pragma unroll
      for (int nt = 0; nt < 8; nt++)  // swapped operands: C row=h, col=query
        acc[mt][nt] = __builtin_amdgcn_mfma_f32_16x16x32_bf16(bfr[nt], afr[mt],
                                                              zf, 0, 0, 0);
#pragma unroll
    for (int nt = 0; nt < 8; nt++) {
      int hb = n0s + nt * 16 + quad * 4;
      f32x4 sv = *(const f32x4*)(s0 + hb);
      f32x4 bvv = *(const f32x4*)(b0 + hb);
#pragma unroll
      for (int mt = 0; mt < 3; mt++) {
        f32x4 fv = *(const f32x4*)(Fr[mt] + hb);
        u16x4 o4;
#pragma unroll
        for (int r = 0; r < 4; r++) {
          float h = (fv[r] + acc[mt][nt][r]) * sv[r] + bvv[r];
          h = h > 0.f ? h : 0.f;
          o4[r] = f2bf(h);
        }
        // LDS stage at [row rl][col nt*16+quad*4] (u16, stride 136)
        *(u16x4*)(hstage + rlv[mt] * 136 + nt * 16 + quad * 4) = o4;
      }
    }
    __syncthreads();
    // coalesced write: 192 rows x 16 chunks of 16B; 12 chunks per thread
#pragma unroll
    for (int it = 0; it < 12; it++) {
      int idx = it * 256 + t;
      int rl = idx >> 4, ch = idx & 15;
      u16x8 v = *(const u16x8*)(hstage + rl * 136 + ch * 8);
      int jj = rl >> 6, ql = rl & 63;
      *(u16x8*)(H0 + ((size_t)(jj * NQ) + qb + ql) * H0Q + n0s + ch * 8) = v;
    }
    __syncthreads();
  }
}

// ---------------------------------------------------------------------------
// gemm2: out[b][n][n1] = sum_j relu((H0_j[q][:] . W1[n][:])*s1[n] + b1[n]).
// BM=128 x BN=128, BK=64, 256 threads = 4 waves (2M x 2N), 64x64 per wave,
// 32 MFMA/wave/step. DOUBLE-buffered LDS (2 x 32KB = 64KB) -> 2 blocks/CU.
// 24 K-steps (3 planes x 8). Per step (R4-proven discipline):
//   vmcnt(8)  [stage kt landed; stage kt+1 in flight]  -> s_barrier
//   16 ds_read_b128 frags -> lgkmcnt(0) -> s_barrier   [buf fully read]
//   stage(kt+2 -> buf kt&1)  [8 global_load_lds/thread]
//   setprio(1) 32 MFMA setprio(0);  relu-fold at kt=7/15/23.
// Swapped-operand MFMA: C rows = gn frags, cols = queries -> epilogue
// writes 4x64B contiguous n1 segments per store instruction.
__global__ __launch_bounds__(256, 2) void gemm2(const u16* __restrict__ A,
                                                const u16* __restrict__ W,
                                                const float* __restrict__ s,
                                                const float* __restrict__ bz,
                                                float* __restrict__ out) {
  __shared__ alignas(16) u16 As[2][128 * 64];  // 16KB per buffer
  __shared__ alignas(16) u16 Bs[2][128 * 64];  // 16KB per buffer
  const int id = blockIdx.x;            // 1024 blocks
  const int xcd = id & 7, g = id >> 3;  // g 0..127
  const int m0 = (xcd * 16 + (g >> 3)) * 128;  // 16 m-tiles per XCD
  const int n0 = (g & 7) * 128;
  const int t = threadIdx.x;
  const int wv = t >> 6, lane = t & 63;  // 4 waves
  const int wm = wv >> 1, wn = wv & 1;   // 2M x 2N wave grid
  const int quad = lane >> 4, cc = lane & 15;
  const int lr = lane & 15, lk = quad * 8;

  // staging source bases (elements); + i*64 rows, + kk*32, + k0 per step
  const size_t aOff = (size_t)(m0 + wv * 16 + lr) * 512 + lk;
  const size_t bOff = (size_t)(n0 + wv * 16 + lr) * 512 + lk;

  // per-lane scale/bias for swapped-C: gn = n0 + wn*64 + nt*16 + quad*4 + r
  f32x4 sv4[4], bv4[4];
#pragma unroll
  for (int nt = 0; nt < 4; nt++) {
    int gnb = n0 + wn * 64 + nt * 16 + quad * 4;
    sv4[nt] = *(const f32x4*)(s + gnb);
    bv4[nt] = *(const f32x4*)(bz + gnb);
  }
  // pin s/b in regs now so no vmcnt(0) drain is injected at the folds
#pragma unroll
  for (int nt = 0; nt < 4; nt++)
#pragma unroll
    for (int r = 0; r < 4; r++) {
      float a = sv4[nt][r], c = bv4[nt][r];
      asm volatile("" : "+v"(a), "+v"(c));
      sv4[nt][r] = a; bv4[nt][r] = c;
    }

  auto stage = [&](int kt, int bi) {
    const u16* Ap = A + (size_t)(kt >> 3) * ((size_t)NQ * H0Q) + ((kt & 7) << 6);
    const u16* Wp = W + ((kt & 7) << 6);
#pragma unroll
    for (int i = 0; i < 2; i++)
#pragma unroll
      for (int kk = 0; kk < 2; kk++) {
        const int grp = kk * 8 + i * 4 + wv;   // 16 x 1KB groups per tile
        load16_lds(Ap + aOff + (size_t)(i * 64) * 512 + kk * 32,
                   (char*)As[bi] + grp * 1024 + (lane << 4));
        load16_lds(Wp + bOff + (size_t)(i * 64) * 512 + kk * 32,
                   (char*)Bs[bi] + grp * 1024 + (lane << 4));
      }
  };

  f32x4 sum[4][4] = {};
  f32x4 acc[4][4] = {};

  auto readfrags = [&](int bi, bf16x8 af[2][4], bf16x8 bf[2][4]) {
    const char* ab = (const char*)As[bi] + (lane << 4);
    const char* bb = (const char*)Bs[bi] + (lane << 4);
#pragma unroll
    for (int kk = 0; kk < 2; kk++)
#pragma unroll
      for (int mt = 0; mt < 4; mt++)
        af[kk][mt] = *(const bf16x8*)(ab + (kk * 8 + wm * 4 + mt) * 1024);
#pragma unroll
    for (int kk = 0; kk < 2; kk++)
#pragma unroll
      for (int nt = 0; nt < 4; nt++)
        bf[kk][nt] = *(const bf16x8*)(bb + (kk * 8 + wn * 4 + nt) * 1024);
  };

  auto mfmas = [&](bf16x8 af[2][4], bf16x8 bf[2][4]) {
    __builtin_amdgcn_s_setprio(1);
#pragma unroll
    for (int kk = 0; kk < 2; kk++)
#pragma unroll
      for (int mt = 0; mt < 4; mt++)
#pragma unroll
        for (int nt = 0; nt < 4; nt++)  // swapped: C row=gn frag, col=query
          acc[mt][nt] = __builtin_amdgcn_mfma_f32_16x16x32_bf16(
              bf[kk][nt], af[kk][mt], acc[mt][nt], 0, 0, 0);
    __builtin_amdgcn_s_setprio(0);
  };

  auto fold = [&]() {
#pragma unroll
    for (int mt = 0; mt < 4; mt++)
#pragma unroll
      for (int nt = 0; nt < 4; nt++) {
#pragma unroll
        for (int r = 0; r < 4; r++) {
          float h = acc[mt][nt][r] * sv4[nt][r] + bv4[nt][r];
          sum[mt][nt][r] += (h > 0.f ? h : 0.f);
        }
        acc[mt][nt] = f32x4{};
      }
  };

  stage(0, 0);
  stage(1, 1);

  for (int kt = 0; kt < 22; kt++) {
    asm volatile("s_waitcnt vmcnt(8)" ::: "memory");  // stage kt landed
    __builtin_amdgcn_s_barrier();
    bf16x8 af[2][4], bf[2][4];
    readfrags(kt & 1, af, bf);
    asm volatile("s_waitcnt lgkmcnt(0)" ::: "memory");
    __builtin_amdgcn_s_barrier();                     // all waves read buf
    stage(kt + 2, kt & 1);                            // overwrite now safe
    mfmas(af, bf);
    if ((kt & 7) == 7) fold();                        // kt 7, 15
  }
  {  // kt = 22 (stage 23 still in flight)
    asm volatile("s_waitcnt vmcnt(8)" ::: "memory");
    __builtin_amdgcn_s_barrier();
    bf16x8 af[2][4], bf[2][4];
    readfrags(0, af, bf);
    mfmas(af, bf);
  }
  {  // kt = 23
    asm volatile("s_waitcnt vmcnt(0)" ::: "memory");
    __builtin_amdgcn_s_barrier();
    bf16x8 af[2][4], bf[2][4];
    readfrags(1, af, bf);
    mfmas(af, bf);
    fold();
  }

  // epilogue: for fixed (nt,mt,r): 16 cc-lanes write 64B-contiguous n1 runs
  // (4 quads -> 4 separate gn rows: 4x64B segments per instruction)
#pragma unroll
  for (int nt = 0; nt < 4; nt++) {
#pragma unroll
    for (int mt = 0; mt < 4; mt++) {
      int q = m0 + wm * 64 + mt * 16 + cc;
      int bb2 = q >> 11, n1 = q & 2047;
#pragma unroll
      for (int r = 0; r < 4; r++) {
        int gn = n0 + wn * 64 + nt * 16 + quad * 4 + r;
        out[((size_t)bb2 * H1Q + gn) * N1Q + n1] = sum[mt][nt][r];
      }
    }
  }
}

// ---------------------------------------------------------------------------
extern "C" void kernel_launch(void* const* d_in, const int* in_sizes, int n_in,
                              void* d_out, int out_size, void* d_ws,
                              size_t ws_size, hipStream_t stream) {
  const float* xyz1 = (const float*)d_in[0];
  const float* xyz2 = (const float*)d_in[1];
  const float* feat2 = (const float*)d_in[2];
  const float* lrf2 = (const float*)d_in[3];
  const float* w_pos = (const float*)d_in[4];
  const float* pscale = (const float*)d_in[5];
  const float* pbias = (const float*)d_in[6];
  const float* w0 = (const float*)d_in[7];
  const float* s0 = (const float*)d_in[8];
  const float* b0 = (const float*)d_in[9];
  const float* w1 = (const float*)d_in[10];
  const float* s1 = (const float*)d_in[11];
  const float* b1 = (const float*)d_in[12];
  float* out = (float*)d_out;

  char* ws = (char*)d_ws;
  u16* w0f = (u16*)(ws + WS_W0F);
  u16* w0p = (u16*)(ws + WS_W0P);
  u16* w1b = (u16*)(ws + WS_W1);
  u16* f2b = (u16*)(ws + WS_F2B);
  float* F = (float*)(ws + WS_F);
  u16* H0 = (u16*)(ws + WS_H0);

  convert_inputs<<<933888 / 256, 256, 0, stream>>>(w0, w1, feat2, w0f, w0p,
                                                   w1b, f2b);
  fgemm<<<32, 256, 0, stream>>>(f2b, w0f, F);
  build_h0<<<NQ / 64, 256, 0, stream>>>(xyz1, xyz2, lrf2, w_pos, pscale,
                                        pbias, w0p, F, s0, b0, H0);
  gemm2<<<1024, 256, 0, stream>>>(H0, w1b, s1, b1, out);
}

// Round 9
// 234.929 us; speedup vs baseline: 1.3620x; 1.0403x over previous
//
#include <hip/hip_runtime.h>

// ---------------------------------------------------------------------------
// PointTransformerForSegmentation, round 14:
//   convert   : bf16-cast w0feat / w0pos / w1 / feat2
//   fgemm     : F[b*128+n2][512] = feat2 . W0feat^T   (f32, tiny GEMM)
//   knn_pos   : NEW. 128 blocks x 512 thr, small LDS. kNN (4-way scan +
//               merge, serial tie order) + pos embed -> posw[3][16384][32]
//               bf16 + idxw[3][16384] in workspace. High wave count; no
//               giant latency-serialized single-block-per-CU kernel.
//   h0        : NEW. 768 blocks x 256 thr, ZERO LDS -> 12+ waves/CU.
//               Streaming H0[r] = relu((F[idx[r]] + posw[r].W0p^T)*s0+b0),
//               plane-major rows r = j*16384+q. Per wave: 16 rows, 32 MFMA
//               (swapped operands, proven layout), F-gather from L2-hot F.
//   gemm2     : R4 verbatim (94.8 us champion): BM=128 x BN=256, BK=64,
//               512 thr, triple-buffered 144KB, counted vmcnt(12/6/0),
//               24 K-tiles, register relu-fold at plane boundaries.
// ---------------------------------------------------------------------------

typedef unsigned short u16;
typedef __bf16 bf16x8 __attribute__((ext_vector_type(8)));
typedef float f32x4 __attribute__((ext_vector_type(4)));
typedef u16 u16x4 __attribute__((ext_vector_type(4)));
typedef u16 u16x8 __attribute__((ext_vector_type(8)));

#define BQ 8
#define N1Q 2048
#define N2Q 128
#define C2Q 256
#define DPOS 32
#define H0Q 512
#define H1Q 1024
#define NQ (BQ * N1Q)   // 16384 queries

// workspace layout (bytes)
#define WS_W0F 0u          // 512*256*2   = 262144
#define WS_W0P 262144u     // 512*32*2    = 32768
#define WS_W1 294912u      // 1024*512*2  = 1048576
#define WS_F2B 1343488u    // 1024*256*2  = 524288
#define WS_F 1867776u      // 1024*512*4  = 2097152
#define WS_H0 3964928u     // 3*16384*512*2 = 50331648
#define WS_POS 54296576u   // 3*16384*32*2 = 3145728
#define WS_IDX 57442304u   // 3*16384*4   = 196608 (end 57638912)

__device__ __forceinline__ u16 f2bf(float f) {
  unsigned int u = __builtin_bit_cast(unsigned int, f);
  return (u16)((u + 0x7FFFu + ((u >> 16) & 1u)) >> 16);
}

__device__ __forceinline__ void load16_lds(const void* g, void* l) {
  __builtin_amdgcn_global_load_lds(
      (const __attribute__((address_space(1))) unsigned int*)g,
      (__attribute__((address_space(3))) unsigned int*)l, 16, 0, 0);
}

// ---------------------------------------------------------------------------
// convert: w0feat (512x256), w0pos (512x32), w1 (1024x512), feat2 (1024x256)
__global__ void convert_inputs(const float* __restrict__ w0,
                               const float* __restrict__ w1,
                               const float* __restrict__ feat2,
                               u16* __restrict__ w0f, u16* __restrict__ w0p,
                               u16* __restrict__ w1b, u16* __restrict__ f2b) {
  int i = blockIdx.x * 256 + threadIdx.x;  // grid covers 933888 exactly
  if (i < 131072) {
    int h = i >> 8, c = i & 255;
    w0f[i] = f2bf(w0[h * 288 + c]);
  } else if (i < 147456) {
    int j = i - 131072;
    int h = j >> 5, c = j & 31;
    w0p[j] = f2bf(w0[h * 288 + 256 + c]);
  } else if (i < 671744) {
    int j = i - 147456;
    w1b[j] = f2bf(w1[j]);
  } else {
    int j = i - 671744;  // < 262144
    f2b[j] = f2bf(feat2[j]);
  }
}

// ---------------------------------------------------------------------------
// fgemm: F[m][n] = sum_k feat2bf[m][k]*w0featbf[n][k], f32 out.
// M=1024 N=512 K=256, 128x128 tile, 32 blocks.
__global__ __launch_bounds__(256, 2) void fgemm(const u16* __restrict__ A,
                                                const u16* __restrict__ W,
                                                float* __restrict__ F) {
  __shared__ alignas(16) u16 As[128 * 32];
  __shared__ alignas(16) u16 Bs[128 * 32];
  const int m0 = (blockIdx.x >> 2) * 128, n0 = (blockIdx.x & 3) * 128;
  const int t = threadIdx.x;
  const int wv = t >> 6, lane = t & 63;
  const int wm = wv >> 1, wn = wv & 1;
  const int quad = lane >> 4, cc = lane & 15;
  const int srow = lane & 15, skc = quad * 8;
  f32x4 acc[4][4] = {};

  for (int k0 = 0; k0 < 256; k0 += 32) {
#pragma unroll
    for (int i = 0; i < 2; i++) {
      int g = i * 4 + wv;
      load16_lds(A + (size_t)(m0 + g * 16 + srow) * 256 + k0 + skc,
                 (char*)As + g * 1024 + (lane << 4));
      load16_lds(W + (size_t)(n0 + g * 16 + srow) * 256 + k0 + skc,
                 (char*)Bs + g * 1024 + (lane << 4));
    }
    __syncthreads();
    bf16x8 af[4], bf[4];
#pragma unroll
    for (int mt = 0; mt < 4; mt++)
      af[mt] = *(const bf16x8*)((const char*)As + (wm * 4 + mt) * 1024 + (lane << 4));
#pragma unroll
    for (int nt = 0; nt < 4; nt++)
      bf[nt] = *(const bf16x8*)((const char*)Bs + (wn * 4 + nt) * 1024 + (lane << 4));
#pragma unroll
    for (int mt = 0; mt < 4; mt++)
#pragma unroll
      for (int nt = 0; nt < 4; nt++)
        acc[mt][nt] = __builtin_amdgcn_mfma_f32_16x16x32_bf16(
            af[mt], bf[nt], acc[mt][nt], 0, 0, 0);
    __syncthreads();
  }

#pragma unroll
  for (int nt = 0; nt < 4; nt++) {
    int gn = n0 + wn * 64 + nt * 16 + cc;
#pragma unroll
    for (int mt = 0; mt < 4; mt++) {
      int gm = m0 + wm * 64 + mt * 16 + quad * 4;
#pragma unroll
      for (int r = 0; r < 4; r++)
        F[(size_t)(gm + r) * H0Q + gn] = acc[mt][nt][r];
    }
  }
}

// ---------------------------------------------------------------------------
// knn_pos: 128 blocks x 512 threads; block = 128 queries (same batch b).
// 1a: 4 threads/query scan 32 points each.  1b: t<128 merge 12 candidates
// (qt-major order == serial tie order).  1c: t<384 = one (query, neighbor):
// pos embed -> posw row (64B contiguous) + idxw.
__global__ __launch_bounds__(512, 2) void knn_pos(
    const float* __restrict__ xyz1, const float* __restrict__ xyz2,
    const float* __restrict__ lrf2, const float* __restrict__ w_pos,
    const float* __restrict__ pscale, const float* __restrict__ pbias,
    u16* __restrict__ posw, int* __restrict__ idxw) {
  __shared__ float xyz2s[N2Q * 3];
  __shared__ float n2s[N2Q];
  __shared__ float lrfs[N2Q * 9];
  __shared__ float wps[DPOS * 4];
  __shared__ float pss[DPOS];
  __shared__ float pbs[DPOS];
  __shared__ float candd[128 * 13];  // stride 13: conflict-free merge reads
  __shared__ int candi[128 * 13];
  __shared__ int idxb[384];

  const int t = threadIdx.x;
  const int qb = blockIdx.x * 128;   // 128 blocks
  const int b = qb >> 11;            // 16 blocks per batch

  for (int i = t; i < N2Q * 3; i += 512) xyz2s[i] = xyz2[b * N2Q * 3 + i];
  for (int i = t; i < N2Q * 9; i += 512) lrfs[i] = lrf2[b * N2Q * 9 + i];
  if (t < DPOS * 4) wps[t] = w_pos[t];
  if (t < DPOS) { pss[t] = pscale[t]; pbs[t] = pbias[t]; }
  __syncthreads();
  if (t < N2Q) {
    float x = xyz2s[t * 3], y = xyz2s[t * 3 + 1], z = xyz2s[t * 3 + 2];
    n2s[t] = x * x + y * y + z * z;
  }
  __syncthreads();

  // ---- 1a: partial kNN, 4 threads per query ----
  {
    const int ql = t >> 2, qt = t & 3;
    const int q = qb + ql;
    const float px = xyz1[q * 3], py = xyz1[q * 3 + 1], pz = xyz1[q * 3 + 2];
    const float pn = px * px + py * py + pz * pz;
    float d0 = 1e30f, d1 = 1e30f, d2v = 1e30f;
    int i0 = 0, i1 = 0, i2 = 0;
    const int ibeg = qt * 32;
    for (int i = ibeg; i < ibeg + 32; i++) {
      float dt = px * xyz2s[i * 3] + py * xyz2s[i * 3 + 1] + pz * xyz2s[i * 3 + 2];
      float d = pn + n2s[i] - 2.f * dt;
      if (d < d0) {
        d2v = d1; i2 = i1; d1 = d0; i1 = i0; d0 = d; i0 = i;
      } else if (d < d1) {
        d2v = d1; i2 = i1; d1 = d; i1 = i;
      } else if (d < d2v) {
        d2v = d; i2 = i;
      }
    }
    int base = ql * 13 + qt * 3;
    candd[base] = d0;      candi[base] = i0;
    candd[base + 1] = d1;  candi[base + 1] = i1;
    candd[base + 2] = d2v; candi[base + 2] = i2;
  }
  __syncthreads();

  // ---- 1b: merge 12 candidates per query (t<128) ----
  if (t < 128) {
    float d0 = 1e30f, d1 = 1e30f, d2v = 1e30f;
    int i0 = 0, i1 = 0, i2 = 0;
    int base = t * 13;
#pragma unroll
    for (int c = 0; c < 12; c++) {
      float d = candd[base + c];
      int id = candi[base + c];
      if (d < d0) {
        d2v = d1; i2 = i1; d1 = d0; i1 = i0; d0 = d; i0 = id;
      } else if (d < d1) {
        d2v = d1; i2 = i1; d1 = d; i1 = id;
      } else if (d < d2v) {
        d2v = d; i2 = id;
      }
    }
    idxb[t] = i0;
    idxb[128 + t] = i1;
    idxb[256 + t] = i2;
  }
  __syncthreads();

  // ---- 1c: pos embed, one (query, neighbor) per thread (t<384) ----
  if (t < 384) {
    const int j = t >> 7, ql = t & 127;
    const int q = qb + ql;
    const float px = xyz1[q * 3], py = xyz1[q * 3 + 1], pz = xyz1[q * 3 + 2];
    const int id = idxb[j * 128 + ql];
    float rx = px - xyz2s[id * 3];
    float ry = py - xyz2s[id * 3 + 1];
    float rz = pz - xyz2s[id * 3 + 2];
    float rn = sqrtf(rx * rx + ry * ry + rz * rz);
    float inv = 1.f / fmaxf(rn, 1e-12f);
    float ux = rx * inv, uy = ry * inv, uz = rz * inv;
    const float* L = lrfs + id * 9;
    float a0 = L[0] * ux + L[1] * uy + L[2] * uz;
    float a1 = L[3] * ux + L[4] * uy + L[5] * uz;
    float a2 = L[6] * ux + L[7] * uy + L[8] * uz;
    const size_t row = (size_t)j * NQ + q;
    idxw[row] = id;
#pragma unroll
    for (int c = 0; c < 4; c++) {
      u16x8 chunk;
#pragma unroll
      for (int e = 0; e < 8; e++) {
        int o = c * 8 + e;
        float v = wps[o * 4] * rn + wps[o * 4 + 1] * a0 + wps[o * 4 + 2] * a1 +
                  wps[o * 4 + 3] * a2;
        v = v * pss[o] + pbs[o];
        v = (v >= 0.f) ? v : 0.2f * v;  // LeakyReLU(0.2)
        chunk[e] = f2bf(v);
      }
      *(u16x8*)(posw + row * 32 + c * 8) = chunk;
    }
  }
}

// ---------------------------------------------------------------------------
// h0: streaming H0 build, zero LDS, 768 blocks x 256 threads (4 waves).
// Wave handles 16 plane-major rows r0..r0+15:
//   afr: posw rows (coalesced 16B/lane);  per nt (32): bfr from w0p,
//   1 MFMA (swapped: C[h-frag][q-row]), F-gather f32x4, s0/b0, relu,
//   u16x4 store to H0 row.
__global__ __launch_bounds__(256, 4) void h0_kernel(
    const u16* __restrict__ posw, const int* __restrict__ idxw,
    const u16* __restrict__ w0p, const float* __restrict__ F,
    const float* __restrict__ s0, const float* __restrict__ b0,
    u16* __restrict__ H0) {
  const int t = threadIdx.x;
  const int wv = t >> 6, lane = t & 63;
  const int quad = lane >> 4, cc = lane & 15;
  const int r0 = (blockIdx.x * 4 + wv) * 16;  // 768*4*16 = 49152 rows

  const int r = r0 + cc;               // this lane's row
  const int q = r & (NQ - 1);
  const int bb = q >> 11;
  const int idv = idxw[r];
  const float* Fr = F + ((size_t)(bb * N2Q + idv)) * H0Q;
  u16* Hr = H0 + (size_t)r * H0Q;

  const bf16x8 afr = *(const bf16x8*)(posw + (size_t)r * 32 + quad * 8);
  const f32x4 zf = {};

#pragma unroll 4
  for (int nt = 0; nt < 32; nt++) {
    const bf16x8 bfr = *(const bf16x8*)(w0p + (nt * 16 + cc) * 32 + quad * 8);
    f32x4 acc = __builtin_amdgcn_mfma_f32_16x16x32_bf16(bfr, afr, zf, 0, 0, 0);
    const int hb = nt * 16 + quad * 4;
    const f32x4 sv = *(const f32x4*)(s0 + hb);
    const f32x4 bv = *(const f32x4*)(b0 + hb);
    const f32x4 fv = *(const f32x4*)(Fr + hb);
    u16x4 o4;
#pragma unroll
    for (int e = 0; e < 4; e++) {
      float h = (fv[e] + acc[e]) * sv[e] + bv[e];
      h = h > 0.f ? h : 0.f;
      o4[e] = f2bf(h);
    }
    *(u16x4*)(Hr + hb) = o4;
  }
}

// ---------------------------------------------------------------------------
// gemm2 (R4 verbatim, 94.8us champion):
// BM=128 (queries) x BN=256 (H1), BK=64. 512 threads = 8 waves (2M x 4N),
// per-wave C = 64x64. 24 K-tiles (3 planes x 8), TRIPLE-buffered (144 KiB).
// Per K-tile: vmcnt(12) -> barrier -> 16 ds_read -> lgkmcnt(0) -> barrier ->
// stage(kt+3) -> 32 MFMA. Tail peels 21/22/23 w/ vmcnt(12/6/0). Fold 7/15/23.
__global__ __launch_bounds__(512, 2) void gemm2(const u16* __restrict__ A,
                                                const u16* __restrict__ W,
                                                const float* __restrict__ s,
                                                const float* __restrict__ bz,
                                                float* __restrict__ out) {
  __shared__ alignas(16) u16 As[3][128 * 64];  // 16 KB per buffer
  __shared__ alignas(16) u16 Bs[3][256 * 64];  // 32 KB per buffer
  const int id = blockIdx.x;            // 512 blocks
  const int xcd = id & 7, g = id >> 3;  // g 0..63
  const int m0 = (xcd * 16 + (g >> 2)) * 128;  // 16 m-tiles per XCD
  const int n0 = (g & 3) * 256;
  const int t = threadIdx.x;
  const int wv = t >> 6, lane = t & 63;
  const int wm = wv >> 2, wn = wv & 3;  // 2M x 4N wave grid
  const int quad = lane >> 4, cc = lane & 15;
  const int lr = lane & 15, lk = (lane >> 4) * 8;

  const size_t aOff = (size_t)(m0 + wv * 16 + lr) * 512 + lk;
  const size_t bOff = (size_t)(n0 + wv * 32 + lr) * 512 + lk;

  float sv[4], bv[4];
#pragma unroll
  for (int nt = 0; nt < 4; nt++) {
    int gn = n0 + wn * 64 + nt * 16 + cc;
    sv[nt] = s[gn];
    bv[nt] = bz[gn];
  }

  auto stage = [&](int kt, int bi) {
    const u16* Ap = A + (size_t)(kt >> 3) * ((size_t)NQ * H0Q) + ((kt & 7) << 6);
    const u16* Wp = W + ((kt & 7) << 6);
    char* ab = (char*)As[bi] + (lane << 4);
    char* bb = (char*)Bs[bi] + (lane << 4);
    load16_lds(Ap + aOff, ab + wv * 1024);
    load16_lds(Ap + aOff + 32, ab + (8 + wv) * 1024);
    load16_lds(Wp + bOff, bb + (wv * 2) * 1024);
    load16_lds(Wp + bOff + (size_t)16 * 512, bb + (wv * 2 + 1) * 1024);
    load16_lds(Wp + bOff + 32, bb + (16 + wv * 2) * 1024);
    load16_lds(Wp + bOff + (size_t)16 * 512 + 32, bb + (16 + wv * 2 + 1) * 1024);
  };

  f32x4 sum[4][4] = {};
  f32x4 acc[4][4] = {};

  auto tile = [&](int bi, int ktStage) {
    bf16x8 af[2][4], bf[2][4];
    const char* ab = (const char*)As[bi] + (lane << 4);
    const char* bb = (const char*)Bs[bi] + (lane << 4);
#pragma unroll
    for (int kk = 0; kk < 2; kk++)
#pragma unroll
      for (int mt = 0; mt < 4; mt++)
        af[kk][mt] = *(const bf16x8*)(ab + (kk * 8 + wm * 4 + mt) * 1024);
#pragma unroll
    for (int kk = 0; kk < 2; kk++)
#pragma unroll
      for (int nt = 0; nt < 4; nt++)
        bf[kk][nt] = *(const bf16x8*)(bb + (kk * 16 + wn * 4 + nt) * 1024);
    asm volatile("s_waitcnt lgkmcnt(0)" ::: "memory");
    __builtin_amdgcn_s_barrier();
    if (ktStage >= 0) stage(ktStage, bi);
    __builtin_amdgcn_s_setprio(1);
#pragma unroll
    for (int kk = 0; kk < 2; kk++)
#pragma unroll
      for (int mt = 0; mt < 4; mt++)
#pragma unroll
        for (int nt = 0; nt < 4; nt++)
          acc[mt][nt] = __builtin_amdgcn_mfma_f32_16x16x32_bf16(
              af[kk][mt], bf[kk][nt], acc[mt][nt], 0, 0, 0);
    __builtin_amdgcn_s_setprio(0);
  };

  auto fold = [&]() {
#pragma unroll
    for (int mt = 0; mt < 4; mt++)
#pragma unroll
      for (int nt = 0; nt < 4; nt++) {
#pragma unroll
        for (int r = 0; r < 4; r++) {
          float h = acc[mt][nt][r] * sv[nt] + bv[nt];
          sum[mt][nt][r] += (h > 0.f ? h : 0.f);
        }
        acc[mt][nt] = f32x4{};
      }
  };

  stage(0, 0);
  stage(1, 1);
  stage(2, 2);

#pragma unroll 3
  for (int kt = 0; kt < 21; kt++) {
    asm volatile("s_waitcnt vmcnt(12)" ::: "memory");
    __builtin_amdgcn_s_barrier();
    tile(kt % 3, kt + 3);
    if ((kt & 7) == 7) fold();  // kt 7, 15: plane boundary
  }
  asm volatile("s_waitcnt vmcnt(12)" ::: "memory");
  __builtin_amdgcn_s_barrier();
  tile(0, -1);  // kt 21
  asm volatile("s_waitcnt vmcnt(6)" ::: "memory");
  __builtin_amdgcn_s_barrier();
  tile(1, -1);  // kt 22
  asm volatile("s_waitcnt vmcnt(0)" ::: "memory");
  __builtin_amdgcn_s_barrier();
  tile(2, -1);  // kt 23
  fold();

#pragma unroll
  for (int nt = 0; nt < 4; nt++) {
    int gn = n0 + wn * 64 + nt * 16 + cc;
#pragma unroll
    for (int mt = 0; mt < 4; mt++) {
      int gm = m0 + wm * 64 + mt * 16 + quad * 4;
#pragma unroll
      for (int r = 0; r < 4; r++) {
        int q = gm + r;
        out[((size_t)(q >> 11) * H1Q + gn) * N1Q + (q & 2047)] = sum[mt][nt][r];
      }
    }
  }
}

// ---------------------------------------------------------------------------
extern "C" void kernel_launch(void* const* d_in, const int* in_sizes, int n_in,
                              void* d_out, int out_size, void* d_ws,
                              size_t ws_size, hipStream_t stream) {
  const float* xyz1 = (const float*)d_in[0];
  const float* xyz2 = (const float*)d_in[1];
  const float* feat2 = (const float*)d_in[2];
  const float* lrf2 = (const float*)d_in[3];
  const float* w_pos = (const float*)d_in[4];
  const float* pscale = (const float*)d_in[5];
  const float* pbias = (const float*)d_in[6];
  const float* w0 = (const float*)d_in[7];
  const float* s0 = (const float*)d_in[8];
  const float* b0 = (const float*)d_in[9];
  const float* w1 = (const float*)d_in[10];
  const float* s1 = (const float*)d_in[11];
  const float* b1 = (const float*)d_in[12];
  float* out = (float*)d_out;

  char* ws = (char*)d_ws;
  u16* w0f = (u16*)(ws + WS_W0F);
  u16* w0p = (u16*)(ws + WS_W0P);
  u16* w1b = (u16*)(ws + WS_W1);
  u16* f2b = (u16*)(ws + WS_F2B);
  float* F = (float*)(ws + WS_F);
  u16* H0 = (u16*)(ws + WS_H0);
  u16* posw = (u16*)(ws + WS_POS);
  int* idxw = (int*)(ws + WS_IDX);

  convert_inputs<<<933888 / 256, 256, 0, stream>>>(w0, w1, feat2, w0f, w0p,
                                                   w1b, f2b);
  fgemm<<<32, 256, 0, stream>>>(f2b, w0f, F);
  knn_pos<<<128, 512, 0, stream>>>(xyz1, xyz2, lrf2, w_pos, pscale, pbias,
                                   posw, idxw);
  h0_kernel<<<768, 256, 0, stream>>>(posw, idxw, w0p, F, s0, b0, H0);
  gemm2<<<512, 512, 0, stream>>>(H0, w1b, s1, b1, out);
}